// Round 2
// baseline (1921.409 us; speedup 1.0000x reference)
//
#include <hip/hip_runtime.h>
#include <cstdint>
#include <cstddef>

typedef unsigned int u32;
typedef unsigned short u16;
typedef unsigned long long u64;

#define NUM_EL 2359296
#define N_ROWS 294912
#define N_OPS  262144
#define OFF1   1048576
#define OFF2   2097152

// ---------------- workspace layout (bytes) ----------------
// addr:    [0, 9437184)            u32[NUM_EL]
// featsM:  [18874368, 56623104)    bf16[NUM_EL*8] memory-position order (37.75MB)
//          sort1 scratch overlays (dead before k_conv):
//    kA=+0, kB=+9437184, v0=+18874368, v1=+28311552
// counts0: [56623104, 56918016)    u32[256*288]  (also gcounts[256*32] for sort2)
// counts1: [56918016, 57212928)    u32[256*288]  (atomic, zeroed in k_front)
// counts2: [57212928, 57507840)    u32[256*288]  (atomic, zeroed in k_front)
// pos:     [57507840, 57802752)    u32[256*288]
// part:    [57802752, 60162048)    float[64*9216]
// flat:    [60162048, 60163072)    float[256]
// wt:      [60163072, 60167680)    float[1152]
// pgp:     [60167680, 60168192)    double[64]
// bar:     [60168192, 60168256)    u32 grid-barrier counter
// ops:     [60168256, 64362560)    float4[N_OPS]
// k2A/k2B/v2A/v2B: [64362560, +4MB)
#define OFF_F8     18874368ull
#define OFF_C0     56623104ull
#define OFF_C1     56918016ull
#define OFF_C2     57212928ull
#define OFF_POS    57507840ull
#define OFF_PART   57802752ull
#define OFF_FLAT   60162048ull
#define OFF_WT     60163072ull
#define OFF_PGP    60167680ull
#define OFF_BAR    60168192ull
#define OFF_OPS    60168256ull
#define OFF_S2     64362560ull

__device__ inline u32 pk_bf16(float a, float b) {  // RNE pack of 2 floats -> 2 bf16
  u32 ua = __float_as_uint(a), ub = __float_as_uint(b);
  ua = (ua + 0x7fffu + ((ua >> 16) & 1u)) >> 16;
  ub = (ub + 0x7fffu + ((ub >> 16) & 1u)) >> 16;
  return ua | (ub << 16);
}

// front: sort1 keys + fused pass-0 histogram (blocks 0..287, 8192-elem tiles),
// weight transpose + barrier-counter zero (block 288).
// Also zeroes counts1/counts2 (atomic next-pass hists built by the scatters).
__global__ __launch_bounds__(256) void k_front(const float* __restrict__ x,
                                               u32* __restrict__ keys,
                                               u32* __restrict__ counts0,
                                               u32* __restrict__ counts1,
                                               u32* __restrict__ counts2,
                                               const float* __restrict__ mw, float* __restrict__ wt,
                                               u32* __restrict__ bar) {
  int b = blockIdx.x, t = threadIdx.x;
  if (b < 288) {
    counts1[b * 256 + t] = 0u;  // 288*256 == 256*288 entries total, coalesced
    counts2[b * 256 + t] = 0u;
    __shared__ u32 h[256];
    h[t] = 0u;
    __syncthreads();
    int base = b * 8192;
#pragma unroll
    for (int k = 0; k < 32; k++) {
      int i = base + k * 256 + t;
      u32 u = __float_as_uint(x[i]);
      u = (u & 0x80000000u) ? ~u : (u | 0x80000000u);
      keys[i] = u;
      atomicAdd(&h[(u >> 8) & 255u], 1u);
    }
    __syncthreads();
    counts0[t * 288 + b] = h[t];  // digit-major
  } else {
    for (int i = t; i < 1152; i += 256) {
      int oc = i & 15;
      int rest = i >> 4;
      int ic = rest & 7;
      int p = rest >> 3;
      int dr = p / 3, dl = p % 3;
      wt[i] = mw[((oc * 8 + ic) * 3 + dr) * 3 + dl];
    }
    if (t == 0) bar[0] = 0u;
  }
}

// 256 blocks (one per digit): base = sum counts[0, d*nB), then row scan in LDS.
__global__ __launch_bounds__(256) void k_scan_par(const u32* __restrict__ counts,
                                                  u32* __restrict__ pos, int nB) {
  int d = blockIdx.x, t = threadIdx.x;
  __shared__ u32 red[256];
  u32 s = 0;
  u32 lim = (u32)(d * nB);
  for (u32 i = t; i < lim; i += 256) s += counts[i];
  red[t] = s;
  __syncthreads();
  for (int off = 128; off > 0; off >>= 1) {
    if (t < off) red[t] += red[t + off];
    __syncthreads();
  }
  u32 base = red[0];
  __syncthreads();
  int chunk = (nB + 255) / 256;
  int i0 = t * chunk;
  u32 loc[4];
  u32 lsum = 0;
#pragma unroll 4
  for (int k = 0; k < chunk; k++) {
    int i = i0 + k;
    u32 v = (i < nB) ? counts[d * nB + i] : 0u;
    loc[k] = lsum;
    lsum += v;
  }
  red[t] = lsum;
  __syncthreads();
  for (int off = 1; off < 256; off <<= 1) {
    u32 y = (t >= off) ? red[t - off] : 0u;
    __syncthreads();
    red[t] += y;
    __syncthreads();
  }
  u32 excl = red[t] - lsum;
#pragma unroll 4
  for (int k = 0; k < chunk; k++) {
    int i = i0 + k;
    if (i < nB) pos[d * nB + i] = base + excl + loc[k];
  }
}

// Stable scatter, 8192 tile, LDS reorder-by-digit -> coalesced global runs.
// gen_iota: vals = global index (pass 0, vin unused).
// mode: 0 = write keys+vals; 1 = write vals only (final pass).
// cnext != null: atomically build next pass's histogram (digit at shift2, out-tile gpos>>13).
__global__ __launch_bounds__(512) void k_scatter(const u32* __restrict__ kin, const u32* __restrict__ vin,
                                                 u32* __restrict__ kout, u32* __restrict__ vout,
                                                 const u32* __restrict__ gbase, int shift, int nB,
                                                 int gen_iota, int mode,
                                                 u32* __restrict__ cnext, int shift2) {
  __shared__ u32 sk[8192], sv[8192];
  __shared__ u32 whist[8][256];
  __shared__ u32 sbase[256], lstart[256], gdelta[256], red[256];
  int t = threadIdx.x, b = blockIdx.x;
  int base = b * 8192;
  if (t < 256) {
#pragma unroll
    for (int w2 = 0; w2 < 8; w2++) whist[w2][t] = 0;
    sbase[t] = gbase[t * nB + b];
  }
  __syncthreads();
  int w = t >> 6, lane = t & 63;
  u64 lowmask = (1ull << lane) - 1ull;
  u32 kk[16], vv[16], dig[16], rnk[16];
#pragma unroll
  for (int j = 0; j < 16; j++) {
    int idx = base + w * 1024 + j * 64 + lane;
    kk[j] = kin[idx];
    vv[j] = gen_iota ? (u32)idx : vin[idx];
  }
#pragma unroll
  for (int j = 0; j < 16; j++) {
    u32 d = (kk[j] >> shift) & 255u;
    u64 m = ~0ull;
#pragma unroll
    for (int bit = 0; bit < 8; bit++) {
      u64 bal = __ballot((d >> bit) & 1u);
      m &= ((d >> bit) & 1u) ? bal : ~bal;
    }
    u32 rr = (u32)__popcll(m & lowmask);
    u32 cnt = (u32)__popcll(m);
    u32 prev = whist[w][d];        // wave-synchronous LDS read
    if (rr == 0) whist[w][d] = prev + cnt;
    dig[j] = d;
    rnk[j] = prev + rr;
  }
  __syncthreads();
  u32 tot = 0;
  if (t < 256) {
    u32 sacc = 0;
#pragma unroll
    for (int ww = 0; ww < 8; ww++) { u32 v = whist[ww][t]; whist[ww][t] = sacc; sacc += v; }
    tot = sacc;
    red[t] = tot;
  }
  __syncthreads();
  for (int off = 1; off < 256; off <<= 1) {
    u32 y = (t < 256 && t >= off) ? red[t - off] : 0u;
    __syncthreads();
    if (t < 256) red[t] += y;
    __syncthreads();
  }
  if (t < 256) {
    u32 lst = red[t] - tot;
    lstart[t] = lst;
    gdelta[t] = sbase[t] - lst;
  }
  __syncthreads();
#pragma unroll
  for (int j = 0; j < 16; j++) {
    u32 d = dig[j];
    u32 lpos = lstart[d] + whist[w][d] + rnk[j];
    sk[lpos] = kk[j];
    sv[lpos] = vv[j];
  }
  __syncthreads();
#pragma unroll
  for (int r = 0; r < 16; r++) {
    int idx = t + r * 512;
    u32 key = sk[idx];
    u32 d = (key >> shift) & 255u;
    u32 gpos = gdelta[d] + (u32)idx;
    u32 val = sv[idx];
    vout[gpos] = val;
    if (mode == 0) kout[gpos] = key;
    if (cnext) atomicAdd(&cnext[((key >> shift2) & 255u) * 288u + (gpos >> 13)], 1u);
  }
}

// merged 3 convs: streaming 1->8ch 3x3 SAME on addr-as-float, relu,
// bf16x8 pack scattered directly to memory-position order featsM[addr[label]].
__global__ __launch_bounds__(256) void k_conv(const u32* __restrict__ addr,
                                              const float* __restrict__ cw0, const float* __restrict__ cb0,
                                              const float* __restrict__ cw1, const float* __restrict__ cb1,
                                              const float* __restrict__ cw2, const float* __restrict__ cb2,
                                              u16* __restrict__ featsM) {
  int b = blockIdx.x;
  int H, W, lw, off;
  const float *cw, *cb;
  int pix;
  if (b < 4096)      { H = 1024; W = 1024; lw = 10; off = 0;    cw = cw0; cb = cb0; pix = b * 256; }
  else if (b < 8192) { H = 1024; W = 1024; lw = 10; off = OFF1; cw = cw1; cb = cb1; pix = (b - 4096) * 256; }
  else               { H = 512;  W = 512;  lw = 9;  off = OFF2; cw = cw2; cb = cb2; pix = (b - 8192) * 256; }
  pix += threadIdx.x;
  int i = pix >> lw, j = pix & (W - 1);
  u32 m = addr[off + pix];  // destination memory position
  float x[3][3];
#pragma unroll
  for (int dr = 0; dr < 3; dr++)
#pragma unroll
    for (int dc = 0; dc < 3; dc++) {
      int r = i + dr - 1, c = j + dc - 1;
      bool inb = ((unsigned)r < (unsigned)H) && ((unsigned)c < (unsigned)W);
      x[dr][dc] = inb ? (float)addr[off + r * W + c] : 0.0f;
    }
  float acc[8];
#pragma unroll
  for (int oc = 0; oc < 8; oc++) {
    float s = cb[oc];
#pragma unroll
    for (int dr = 0; dr < 3; dr++)
#pragma unroll
      for (int dc = 0; dc < 3; dc++)
        s = fmaf(x[dr][dc], cw[oc * 9 + dr * 3 + dc], s);
    acc[oc] = fmaxf(s, 0.0f);
  }
  uint4 pk;
  pk.x = pk_bf16(acc[0], acc[1]);
  pk.y = pk_bf16(acc[2], acc[3]);
  pk.z = pk_bf16(acc[4], acc[5]);
  pk.w = pk_bf16(acc[6], acc[7]);
  *(uint4*)(featsM + (size_t)m * 8) = pk;
}

// 8->16ch 3x3 conv + fused 4x4 pool, fully coalesced reads from featsM.
__global__ __launch_bounds__(256) void k_memconv(const u16* __restrict__ featsM,
                                                 const float* __restrict__ wt,
                                                 const float* __restrict__ mb,
                                                 float* __restrict__ partials) {
  __shared__ float tile[34 * 80];
  __shared__ float pool_s[256 * 17];
  int t = threadIdx.x;
  int r0 = blockIdx.x * 32;
  for (int idx = t; idx < 34 * 8; idx += 256) {
    int rr = idx >> 3, g = idx & 7;
    int r = r0 - 1 + rr;
    float f[8];
    if ((unsigned)r < (unsigned)N_ROWS) {
      uint4 u = *(const uint4*)(featsM + (size_t)(r * 8 + g) * 8);
      f[0] = __uint_as_float(u.x << 16); f[1] = __uint_as_float(u.x & 0xffff0000u);
      f[2] = __uint_as_float(u.y << 16); f[3] = __uint_as_float(u.y & 0xffff0000u);
      f[4] = __uint_as_float(u.z << 16); f[5] = __uint_as_float(u.z & 0xffff0000u);
      f[6] = __uint_as_float(u.w << 16); f[7] = __uint_as_float(u.w & 0xffff0000u);
    } else {
#pragma unroll
      for (int c = 0; c < 8; c++) f[c] = 0.0f;
    }
#pragma unroll
    for (int c = 0; c < 8; c++) tile[rr * 80 + (g + 1) * 8 + c] = f[c];
  }
  for (int idx = t; idx < 34 * 16; idx += 256) {
    int rr = idx >> 4, k = idx & 15;
    int col = (k < 8) ? k : (64 + k);
    tile[rr * 80 + col] = 0.0f;
  }
  __syncthreads();
  int lr = t >> 3, l = t & 7;
  float acc[16];
#pragma unroll
  for (int oc = 0; oc < 16; oc++) acc[oc] = mb[oc];
#pragma unroll
  for (int dr = 0; dr < 3; dr++) {
#pragma unroll
    for (int dl = 0; dl < 3; dl++) {
      const float* src = &tile[(lr + dr) * 80 + (l + dl) * 8];
      float4 a0 = *(const float4*)(src);
      float4 a1 = *(const float4*)(src + 4);
      float xv[8] = {a0.x, a0.y, a0.z, a0.w, a1.x, a1.y, a1.z, a1.w};
      const float* wp = &wt[(dr * 3 + dl) * 128];
#pragma unroll
      for (int ic = 0; ic < 8; ic++) {
#pragma unroll
        for (int oc = 0; oc < 16; oc++)
          acc[oc] = fmaf(xv[ic], wp[ic * 16 + oc], acc[oc]);
      }
    }
  }
#pragma unroll
  for (int oc = 0; oc < 16; oc++) pool_s[t * 17 + oc] = fmaxf(acc[oc], 0.0f);
  __syncthreads();
  if (t < 64) {
    int oc = t >> 2, lb = t & 3;
    float s = 0.0f;
    for (int lr2 = 0; lr2 < 32; lr2++) {
      int t2 = lr2 * 8 + lb * 2;
      s += pool_s[t2 * 17 + oc] + pool_s[(t2 + 1) * 17 + oc];
    }
    partials[(size_t)(oc * 4 + lb) * 9216 + blockIdx.x] = s;
  }
}

__global__ __launch_bounds__(256) void k_pool_final(const float* __restrict__ partials,
                                                    float* __restrict__ flat) {
  int f = blockIdx.x;
  int oc = f >> 4, rb = (f >> 2) & 3, lb = f & 3;
  const float* src = partials + (size_t)(oc * 4 + lb) * 9216 + rb * 2304;
  double s = 0.0;
  for (int i = threadIdx.x; i < 2304; i += 256) s += (double)src[i];
  __shared__ double sd[256];
  sd[threadIdx.x] = s;
  __syncthreads();
  for (int off = 128; off > 0; off >>= 1) {
    if (threadIdx.x < off) sd[threadIdx.x] += sd[threadIdx.x + off];
    __syncthreads();
  }
  if (threadIdx.x == 0) flat[f] = (float)(sd[0] * (1.0 / 147456.0));
}

// one wave per 32 rows of proj_w; also emits sort2 keys+vals
__global__ __launch_bounds__(256) void k_matvec(const float* __restrict__ pw,
                                                const float* __restrict__ pb,
                                                const float* __restrict__ flat,
                                                float* __restrict__ out,
                                                u32* __restrict__ k2, u32* __restrict__ v2) {
  int t = threadIdx.x;
  int lane = t & 63;
  int g = (blockIdx.x * 256 + t) >> 6;
  float4 f4 = ((const float4*)flat)[lane];
  int row0 = g * 32;
  for (int it = 0; it < 32; it += 2) {
    int row = row0 + it;
    float4 wa = ((const float4*)(pw + (size_t)row * 256))[lane];
    float4 wb = ((const float4*)(pw + (size_t)(row + 1) * 256))[lane];
    float sa = wa.x * f4.x + wa.y * f4.y + wa.z * f4.z + wa.w * f4.w;
    float sb = wb.x * f4.x + wb.y * f4.y + wb.z * f4.z + wb.w * f4.w;
#pragma unroll
    for (int off = 32; off > 0; off >>= 1) {
      sa += __shfl_xor(sa, off, 64);
      sb += __shfl_xor(sb, off, 64);
    }
    if (lane == 0) {
      float ra = sa + pb[row], rb2 = sb + pb[row + 1];
      out[row] = ra;
      out[row + 1] = rb2;
      u32 ua = __float_as_uint(ra), ub = __float_as_uint(rb2);
      ua = (ua & 0x80000000u) ? ~ua : (ua | 0x80000000u);
      ub = (ub & 0x80000000u) ? ~ub : (ub | 0x80000000u);
      k2[row] = ua; k2[row + 1] = ub;
      v2[row] = (u32)row; v2[row + 1] = (u32)(row + 1);
    }
  }
}

__device__ inline double staged_pair(float x) {
  float h = fabsf(x);
  double mult = (h <= 2.f) ? 1.0 : (h <= 4.f) ? 1.5 : (h <= 8.f) ? 2.0 : (h <= 16.f) ? 3.0 : 5.0;
  double hh = (double)h;
  if (x > 0.f) return hh * mult;
  if (x < 0.f) return hh * hh * mult;
  return 0.0;
}

// grid barrier: monotonic counter, release/acquire fences (rocPRIM-style).
// All 32 blocks co-resident (32 << 256 CUs), uniform call count.
__device__ __forceinline__ void gb(u32* bar, u32 target, int t) {
  __syncthreads();
  if (t == 0) {
    __threadfence();                 // release: make our writes visible
    atomicAdd(bar, 1u);
    while (atomicAdd(bar, 0u) < target) __builtin_amdgcn_s_sleep(1);
    __threadfence();                 // acquire: invalidate stale cached lines
  }
  __syncthreads();
}

// FUSED sort2 (3 radix passes) + ops emission + penalty + finalize.
// 32 blocks x 512 threads, persistent, device-atomic grid barrier.
__global__ __launch_bounds__(512) void k_sort2(u32* __restrict__ kA, u32* __restrict__ vA,
                                               u32* __restrict__ kB, u32* __restrict__ vB,
                                               u32* __restrict__ gcounts,
                                               const u32* __restrict__ addr,
                                               float4* __restrict__ ops,
                                               double* __restrict__ pgp,
                                               u32* __restrict__ bar,
                                               float* __restrict__ out) {
  __shared__ __attribute__((aligned(16))) char smem[76 * 1024];
  u32* sk = (u32*)smem;                               // 8192
  u32* sv = sk + 8192;                                // 8192
  u32 (*whist)[256] = (u32(*)[256])(sv + 8192);       // 8*256
  u32* sbase  = (u32*)(smem + 72 * 1024);             // 256
  u32* lstart = sbase + 256;                          // 256
  u32* gdelta = lstart + 256;                         // 256
  u32* red    = gdelta + 256;                         // 256
  int t = threadIdx.x, b = blockIdx.x;
  int w = t >> 6, lane = t & 63;
  u64 lowmask = (1ull << lane) - 1ull;
  int base = b * 8192;
  u32 barn = 0;

  for (int pass = 0; pass < 3; pass++) {
    int shift = 8 + pass * 8;
    const u32* kin = (pass == 1) ? kB : kA;
    const u32* vin = (pass == 1) ? vB : vA;
    u32* kout = (pass == 0) ? kB : kA;
    u32* vout = (pass == 0) ? vB : vA;

    // ---- hist (per-block tile) ----
    u32* h = whist[0];
    if (t < 256) h[t] = 0u;
    __syncthreads();
#pragma unroll
    for (int k = 0; k < 16; k++) {
      u32 d = (kin[base + t + k * 512] >> shift) & 255u;
      atomicAdd(&h[d], 1u);
    }
    __syncthreads();
    if (t < 256) gcounts[t * 32 + b] = h[t];
    barn += 32;
    gb(bar, barn, t);

    // ---- scan (per-block redundant over 256x32 counts) ----
    u32 rs = 0, part = 0;
    if (t < 256) {
      for (int bb = 0; bb < 32; bb++) {
        u32 c = gcounts[t * 32 + bb];
        rs += c;
        if (bb < b) part += c;
      }
      red[t] = rs;
    }
    __syncthreads();
    for (int off = 1; off < 256; off <<= 1) {
      u32 y = (t < 256 && t >= off) ? red[t - off] : 0u;
      __syncthreads();
      if (t < 256) red[t] += y;
      __syncthreads();
    }
    if (t < 256) sbase[t] = red[t] - rs + part;
    __syncthreads();

    // ---- rank + LDS reorder ----
    if (t < 256) {
#pragma unroll
      for (int ww = 0; ww < 8; ww++) whist[ww][t] = 0u;
    }
    __syncthreads();
    u32 kk[16], vv[16], dig[16], rnk[16];
#pragma unroll
    for (int j = 0; j < 16; j++) {
      int idx = base + w * 1024 + j * 64 + lane;
      kk[j] = kin[idx];
      vv[j] = vin[idx];
    }
#pragma unroll
    for (int j = 0; j < 16; j++) {
      u32 d = (kk[j] >> shift) & 255u;
      u64 m = ~0ull;
#pragma unroll
      for (int bit = 0; bit < 8; bit++) {
        u64 bal = __ballot((d >> bit) & 1u);
        m &= ((d >> bit) & 1u) ? bal : ~bal;
      }
      u32 rr = (u32)__popcll(m & lowmask);
      u32 cnt = (u32)__popcll(m);
      u32 prev = whist[w][d];
      if (rr == 0) whist[w][d] = prev + cnt;
      dig[j] = d;
      rnk[j] = prev + rr;
    }
    __syncthreads();
    u32 tot = 0;
    if (t < 256) {
      u32 sacc = 0;
#pragma unroll
      for (int ww = 0; ww < 8; ww++) { u32 v = whist[ww][t]; whist[ww][t] = sacc; sacc += v; }
      tot = sacc;
      red[t] = tot;
    }
    __syncthreads();
    for (int off = 1; off < 256; off <<= 1) {
      u32 y = (t < 256 && t >= off) ? red[t - off] : 0u;
      __syncthreads();
      if (t < 256) red[t] += y;
      __syncthreads();
    }
    if (t < 256) {
      u32 lst = red[t] - tot;
      lstart[t] = lst;
      gdelta[t] = sbase[t] - lst;
    }
    __syncthreads();
#pragma unroll
    for (int j = 0; j < 16; j++) {
      u32 d = dig[j];
      u32 lpos = lstart[d] + whist[w][d] + rnk[j];
      sk[lpos] = kk[j];
      sv[lpos] = vv[j];
    }
    __syncthreads();

    // ---- write ----
    if (pass < 2) {
#pragma unroll
      for (int r = 0; r < 16; r++) {
        int idx = t + r * 512;
        u32 key = sk[idx];
        u32 d = (key >> shift) & 255u;
        u32 gpos = gdelta[d] + (u32)idx;
        kout[gpos] = key;
        vout[gpos] = sv[idx];
      }
    } else {
#pragma unroll
      for (int r = 0; r < 16; r++) {
        int idx = t + r * 512;
        u32 key = sk[idx];
        u32 d = (key >> shift) & 255u;
        u32 gpos = gdelta[d] + (u32)idx;
        u32 rv = sv[idx];
        int i = (int)(rv >> 9), jj = (int)(rv & 511);
        float A0 = (float)addr[(i << 10) + jj];
        float A1 = (float)addr[OFF1 + (i << 10) + jj];
        float A2 = (float)addr[OFF2 + (int)rv];
        ops[gpos] = make_float4(A0, A1, A2, 0.0f);
      }
    }
    barn += 32;
    gb(bar, barn, t);
  }

  // ---- penalty (ops fully written) ----
  double i0 = 0.0, i1 = 0.0;
#pragma unroll
  for (int r = 0; r < 16; r++) {
    int k = base + r * 512 + t;
    float4 a = ops[k];
    i1 += staged_pair(a.y - a.x) + staged_pair(a.z - a.y);
    if (k < N_OPS - 1) {
      float4 nb = ops[k + 1];
      i0 += staged_pair(nb.x - a.z);
    }
  }
  double* s0 = (double*)smem;        // 512 doubles
  double* s1 = s0 + 512;             // 512 doubles
  s0[t] = i0;
  s1[t] = i1;
  __syncthreads();
  for (int off = 256; off > 0; off >>= 1) {
    if (t < off) { s0[t] += s0[t + off]; s1[t] += s1[t + off]; }
    __syncthreads();
  }
  if (t == 0) { pgp[b] = s0[0]; pgp[32 + b] = s1[0]; }
  barn += 32;
  gb(bar, barn, t);
  if (b == 0 && t == 0) {
    double a0 = 0.0, a1 = 0.0;
    for (int i2 = 0; i2 < 32; i2++) { a0 += pgp[i2]; a1 += pgp[32 + i2]; }
    out[N_OPS] = (float)a0;
    out[N_OPS + 1] = (float)a1;
  }
}

extern "C" void kernel_launch(void* const* d_in, const int* in_sizes, int n_in,
                              void* d_out, int out_size, void* d_ws, size_t ws_size,
                              hipStream_t stream) {
  const float* mem_logits = (const float*)d_in[0];
  const float* cw0 = (const float*)d_in[1];
  const float* cb0 = (const float*)d_in[2];
  const float* cw1 = (const float*)d_in[3];
  const float* cb1 = (const float*)d_in[4];
  const float* cw2 = (const float*)d_in[5];
  const float* cb2 = (const float*)d_in[6];
  const float* mw  = (const float*)d_in[7];
  const float* mbb = (const float*)d_in[8];
  const float* pw  = (const float*)d_in[9];
  const float* pb  = (const float*)d_in[10];
  float* out = (float*)d_out;
  char* ws = (char*)d_ws;

  u32* addr      = (u32*)(ws);
  u16* featsM    = (u16*)(ws + OFF_F8);
  u32* kA        = (u32*)(ws + OFF_F8);
  u32* kB        = (u32*)(ws + OFF_F8 + 9437184ull);
  u32* v0        = (u32*)(ws + OFF_F8 + 18874368ull);
  u32* v1        = (u32*)(ws + OFF_F8 + 28311552ull);
  u32* counts0   = (u32*)(ws + OFF_C0);
  u32* counts1   = (u32*)(ws + OFF_C1);
  u32* counts2   = (u32*)(ws + OFF_C2);
  u32* pos       = (u32*)(ws + OFF_POS);
  float* partials= (float*)(ws + OFF_PART);
  float* flat    = (float*)(ws + OFF_FLAT);
  float* wt      = (float*)(ws + OFF_WT);
  double* pgp    = (double*)(ws + OFF_PGP);
  u32* bar       = (u32*)(ws + OFF_BAR);
  float4* ops    = (float4*)(ws + OFF_OPS);
  u32* k2A       = (u32*)(ws + OFF_S2);
  u32* k2B       = (u32*)(ws + OFF_S2 + 1048576ull);
  u32* v2A       = (u32*)(ws + OFF_S2 + 2097152ull);
  u32* v2B       = (u32*)(ws + OFF_S2 + 3145728ull);

  // ---- sort1: keys + pass-0 hist fused in front; next-pass hists fused in scatters ----
  k_front<<<289, 256, 0, stream>>>(mem_logits, kA, counts0, counts1, counts2, mw, wt, bar);
  k_scan_par<<<256, 256, 0, stream>>>(counts0, pos, 288);
  k_scatter<<<288, 512, 0, stream>>>(kA, nullptr, kB, v0, pos, 8, 288, 1, 0, counts1, 16);
  k_scan_par<<<256, 256, 0, stream>>>(counts1, pos, 288);
  k_scatter<<<288, 512, 0, stream>>>(kB, v0, kA, v1, pos, 16, 288, 0, 0, counts2, 24);
  k_scan_par<<<256, 256, 0, stream>>>(counts2, pos, 288);
  k_scatter<<<288, 512, 0, stream>>>(kA, v1, nullptr, addr, pos, 24, 288, 0, 1, nullptr, 0);

  // ---- streaming convs (scatter to memory order), coalesced memconv + pool ----
  k_conv<<<9216, 256, 0, stream>>>(addr, cw0, cb0, cw1, cb1, cw2, cb2, featsM);
  k_memconv<<<9216, 256, 0, stream>>>(featsM, wt, mbb, partials);
  k_pool_final<<<256, 256, 0, stream>>>(partials, flat);

  // ---- projection matvec -> op_logits + sort2 keys ----
  k_matvec<<<2048, 256, 0, stream>>>(pw, pb, flat, out, k2A, v2A);

  // ---- fused sort2 + ops + penalty + finalize (persistent, grid barrier) ----
  k_sort2<<<32, 512, 0, stream>>>(k2A, v2A, k2B, v2B, counts0, addr, ops, pgp, bar, out);
}

// Round 3
// 822.255 us; speedup vs baseline: 2.3368x; 2.3368x over previous
//
#include <hip/hip_runtime.h>
#include <cstdint>
#include <cstddef>

typedef unsigned int u32;
typedef unsigned short u16;
typedef unsigned long long u64;

#define NUM_EL 2359296
#define N_ROWS 294912
#define N_OPS  262144
#define OFF1   1048576
#define OFF2   2097152

// ---------------- workspace layout (bytes) ----------------
// addr:    [0, 9437184)            u32[NUM_EL]
// featsM:  [18874368, 56623104)    bf16[NUM_EL*8] memory-position order (37.75MB)
//          sort1 scratch overlays (dead before k_conv):
//    kA=+0, kB=+9437184, v0=+18874368, v1=+28311552
// counts0: [56623104, 56918016)    u32[256*288]  (also gcounts[256*32] for sort2)
// pos:     [57507840, 57802752)    u32[256*288]
// part:    [57802752, 60162048)    float[64*9216]
// flat:    [60162048, 60163072)    float[256]
// wt:      [60163072, 60167680)    float[1152]
// pgp:     [60167680, 60168192)    double[64]
// bar:     [60168192, 60168256)    u32 grid-barrier counter
// ops:     [60168256, 64362560)    float4[N_OPS]
// k2A/k2B/v2A/v2B: [64362560, +4MB)
#define OFF_F8     18874368ull
#define OFF_C0     56623104ull
#define OFF_POS    57507840ull
#define OFF_PART   57802752ull
#define OFF_FLAT   60162048ull
#define OFF_WT     60163072ull
#define OFF_PGP    60167680ull
#define OFF_BAR    60168192ull
#define OFF_OPS    60168256ull
#define OFF_S2     64362560ull

__device__ inline u32 pk_bf16(float a, float b) {  // RNE pack of 2 floats -> 2 bf16
  u32 ua = __float_as_uint(a), ub = __float_as_uint(b);
  ua = (ua + 0x7fffu + ((ua >> 16) & 1u)) >> 16;
  ub = (ub + 0x7fffu + ((ub >> 16) & 1u)) >> 16;
  return ua | (ub << 16);
}

// front: sort1 keys + fused pass-0 histogram (blocks 0..287, 8192-elem tiles, LDS atomics only),
// weight transpose + barrier-counter zero (block 288).
__global__ __launch_bounds__(256) void k_front(const float* __restrict__ x,
                                               u32* __restrict__ keys,
                                               u32* __restrict__ counts0,
                                               const float* __restrict__ mw, float* __restrict__ wt,
                                               u32* __restrict__ bar) {
  int b = blockIdx.x, t = threadIdx.x;
  if (b < 288) {
    __shared__ u32 h[256];
    h[t] = 0u;
    __syncthreads();
    int base = b * 8192;
#pragma unroll
    for (int k = 0; k < 32; k++) {
      int i = base + k * 256 + t;
      u32 u = __float_as_uint(x[i]);
      u = (u & 0x80000000u) ? ~u : (u | 0x80000000u);
      keys[i] = u;
      atomicAdd(&h[(u >> 8) & 255u], 1u);
    }
    __syncthreads();
    counts0[t * 288 + b] = h[t];  // digit-major
  } else {
    for (int i = t; i < 1152; i += 256) {
      int oc = i & 15;
      int rest = i >> 4;
      int ic = rest & 7;
      int p = rest >> 3;
      int dr = p / 3, dl = p % 3;
      wt[i] = mw[((oc * 8 + ic) * 3 + dr) * 3 + dl];
    }
    if (t == 0) bar[0] = 0u;
  }
}

// 512 threads, 8192-elem tile, 16 keys/thread. LDS histogram, coalesced output.
__global__ __launch_bounds__(512) void k_hist(const u32* __restrict__ keys,
                                              u32* __restrict__ counts, int shift, int nB) {
  __shared__ u32 h[256];
  int t = threadIdx.x;
  if (t < 256) h[t] = 0;
  __syncthreads();
  int base = blockIdx.x * 8192;
#pragma unroll
  for (int k = 0; k < 16; k++) {
    u32 d = (keys[base + t + k * 512] >> shift) & 255u;
    atomicAdd(&h[d], 1u);
  }
  __syncthreads();
  if (t < 256) counts[t * nB + blockIdx.x] = h[t];  // digit-major
}

// 256 blocks (one per digit): base = sum counts[0, d*nB), then row scan in LDS.
__global__ __launch_bounds__(256) void k_scan_par(const u32* __restrict__ counts,
                                                  u32* __restrict__ pos, int nB) {
  int d = blockIdx.x, t = threadIdx.x;
  __shared__ u32 red[256];
  u32 s = 0;
  u32 lim = (u32)(d * nB);
  for (u32 i = t; i < lim; i += 256) s += counts[i];
  red[t] = s;
  __syncthreads();
  for (int off = 128; off > 0; off >>= 1) {
    if (t < off) red[t] += red[t + off];
    __syncthreads();
  }
  u32 base = red[0];
  __syncthreads();
  int chunk = (nB + 255) / 256;
  int i0 = t * chunk;
  u32 loc[4];
  u32 lsum = 0;
#pragma unroll 4
  for (int k = 0; k < chunk; k++) {
    int i = i0 + k;
    u32 v = (i < nB) ? counts[d * nB + i] : 0u;
    loc[k] = lsum;
    lsum += v;
  }
  red[t] = lsum;
  __syncthreads();
  for (int off = 1; off < 256; off <<= 1) {
    u32 y = (t >= off) ? red[t - off] : 0u;
    __syncthreads();
    red[t] += y;
    __syncthreads();
  }
  u32 excl = red[t] - lsum;
#pragma unroll 4
  for (int k = 0; k < chunk; k++) {
    int i = i0 + k;
    if (i < nB) pos[d * nB + i] = base + excl + loc[k];
  }
}

// Stable scatter, 8192 tile, LDS reorder-by-digit -> coalesced global runs.
// gen_iota: vals = global index (pass 0, vin unused).
// mode: 0 = write keys+vals; 1 = write vals only (final pass).
__global__ __launch_bounds__(512) void k_scatter(const u32* __restrict__ kin, const u32* __restrict__ vin,
                                                 u32* __restrict__ kout, u32* __restrict__ vout,
                                                 const u32* __restrict__ gbase, int shift, int nB,
                                                 int gen_iota, int mode) {
  __shared__ u32 sk[8192], sv[8192];
  __shared__ u32 whist[8][256];
  __shared__ u32 sbase[256], lstart[256], gdelta[256], red[256];
  int t = threadIdx.x, b = blockIdx.x;
  int base = b * 8192;
  if (t < 256) {
#pragma unroll
    for (int w2 = 0; w2 < 8; w2++) whist[w2][t] = 0;
    sbase[t] = gbase[t * nB + b];
  }
  __syncthreads();
  int w = t >> 6, lane = t & 63;
  u64 lowmask = (1ull << lane) - 1ull;
  u32 kk[16], vv[16], dig[16], rnk[16];
#pragma unroll
  for (int j = 0; j < 16; j++) {
    int idx = base + w * 1024 + j * 64 + lane;
    kk[j] = kin[idx];
    vv[j] = gen_iota ? (u32)idx : vin[idx];
  }
#pragma unroll
  for (int j = 0; j < 16; j++) {
    u32 d = (kk[j] >> shift) & 255u;
    u64 m = ~0ull;
#pragma unroll
    for (int bit = 0; bit < 8; bit++) {
      u64 bal = __ballot((d >> bit) & 1u);
      m &= ((d >> bit) & 1u) ? bal : ~bal;
    }
    u32 rr = (u32)__popcll(m & lowmask);
    u32 cnt = (u32)__popcll(m);
    u32 prev = whist[w][d];        // wave-synchronous LDS read
    if (rr == 0) whist[w][d] = prev + cnt;
    dig[j] = d;
    rnk[j] = prev + rr;
  }
  __syncthreads();
  u32 tot = 0;
  if (t < 256) {
    u32 sacc = 0;
#pragma unroll
    for (int ww = 0; ww < 8; ww++) { u32 v = whist[ww][t]; whist[ww][t] = sacc; sacc += v; }
    tot = sacc;
    red[t] = tot;
  }
  __syncthreads();
  for (int off = 1; off < 256; off <<= 1) {
    u32 y = (t < 256 && t >= off) ? red[t - off] : 0u;
    __syncthreads();
    if (t < 256) red[t] += y;
    __syncthreads();
  }
  if (t < 256) {
    u32 lst = red[t] - tot;
    lstart[t] = lst;
    gdelta[t] = sbase[t] - lst;
  }
  __syncthreads();
#pragma unroll
  for (int j = 0; j < 16; j++) {
    u32 d = dig[j];
    u32 lpos = lstart[d] + whist[w][d] + rnk[j];
    sk[lpos] = kk[j];
    sv[lpos] = vv[j];
  }
  __syncthreads();
#pragma unroll
  for (int r = 0; r < 16; r++) {
    int idx = t + r * 512;
    u32 key = sk[idx];
    u32 d = (key >> shift) & 255u;
    u32 gpos = gdelta[d] + (u32)idx;
    u32 val = sv[idx];
    vout[gpos] = val;
    if (mode == 0) kout[gpos] = key;
  }
}

// merged 3 convs: streaming 1->8ch 3x3 SAME on addr-as-float, relu,
// bf16x8 pack scattered directly to memory-position order featsM[addr[label]].
__global__ __launch_bounds__(256) void k_conv(const u32* __restrict__ addr,
                                              const float* __restrict__ cw0, const float* __restrict__ cb0,
                                              const float* __restrict__ cw1, const float* __restrict__ cb1,
                                              const float* __restrict__ cw2, const float* __restrict__ cb2,
                                              u16* __restrict__ featsM) {
  int b = blockIdx.x;
  int H, W, lw, off;
  const float *cw, *cb;
  int pix;
  if (b < 4096)      { H = 1024; W = 1024; lw = 10; off = 0;    cw = cw0; cb = cb0; pix = b * 256; }
  else if (b < 8192) { H = 1024; W = 1024; lw = 10; off = OFF1; cw = cw1; cb = cb1; pix = (b - 4096) * 256; }
  else               { H = 512;  W = 512;  lw = 9;  off = OFF2; cw = cw2; cb = cb2; pix = (b - 8192) * 256; }
  pix += threadIdx.x;
  int i = pix >> lw, j = pix & (W - 1);
  u32 m = addr[off + pix];  // destination memory position
  float x[3][3];
#pragma unroll
  for (int dr = 0; dr < 3; dr++)
#pragma unroll
    for (int dc = 0; dc < 3; dc++) {
      int r = i + dr - 1, c = j + dc - 1;
      bool inb = ((unsigned)r < (unsigned)H) && ((unsigned)c < (unsigned)W);
      x[dr][dc] = inb ? (float)addr[off + r * W + c] : 0.0f;
    }
  float acc[8];
#pragma unroll
  for (int oc = 0; oc < 8; oc++) {
    float s = cb[oc];
#pragma unroll
    for (int dr = 0; dr < 3; dr++)
#pragma unroll
      for (int dc = 0; dc < 3; dc++)
        s = fmaf(x[dr][dc], cw[oc * 9 + dr * 3 + dc], s);
    acc[oc] = fmaxf(s, 0.0f);
  }
  uint4 pk;
  pk.x = pk_bf16(acc[0], acc[1]);
  pk.y = pk_bf16(acc[2], acc[3]);
  pk.z = pk_bf16(acc[4], acc[5]);
  pk.w = pk_bf16(acc[6], acc[7]);
  *(uint4*)(featsM + (size_t)m * 8) = pk;
}

// 8->16ch 3x3 conv + fused 4x4 pool, fully coalesced reads from featsM.
__global__ __launch_bounds__(256) void k_memconv(const u16* __restrict__ featsM,
                                                 const float* __restrict__ wt,
                                                 const float* __restrict__ mb,
                                                 float* __restrict__ partials) {
  __shared__ float tile[34 * 80];
  __shared__ float pool_s[256 * 17];
  int t = threadIdx.x;
  int r0 = blockIdx.x * 32;
  for (int idx = t; idx < 34 * 8; idx += 256) {
    int rr = idx >> 3, g = idx & 7;
    int r = r0 - 1 + rr;
    float f[8];
    if ((unsigned)r < (unsigned)N_ROWS) {
      uint4 u = *(const uint4*)(featsM + (size_t)(r * 8 + g) * 8);
      f[0] = __uint_as_float(u.x << 16); f[1] = __uint_as_float(u.x & 0xffff0000u);
      f[2] = __uint_as_float(u.y << 16); f[3] = __uint_as_float(u.y & 0xffff0000u);
      f[4] = __uint_as_float(u.z << 16); f[5] = __uint_as_float(u.z & 0xffff0000u);
      f[6] = __uint_as_float(u.w << 16); f[7] = __uint_as_float(u.w & 0xffff0000u);
    } else {
#pragma unroll
      for (int c = 0; c < 8; c++) f[c] = 0.0f;
    }
#pragma unroll
    for (int c = 0; c < 8; c++) tile[rr * 80 + (g + 1) * 8 + c] = f[c];
  }
  for (int idx = t; idx < 34 * 16; idx += 256) {
    int rr = idx >> 4, k = idx & 15;
    int col = (k < 8) ? k : (64 + k);
    tile[rr * 80 + col] = 0.0f;
  }
  __syncthreads();
  int lr = t >> 3, l = t & 7;
  float acc[16];
#pragma unroll
  for (int oc = 0; oc < 16; oc++) acc[oc] = mb[oc];
#pragma unroll
  for (int dr = 0; dr < 3; dr++) {
#pragma unroll
    for (int dl = 0; dl < 3; dl++) {
      const float* src = &tile[(lr + dr) * 80 + (l + dl) * 8];
      float4 a0 = *(const float4*)(src);
      float4 a1 = *(const float4*)(src + 4);
      float xv[8] = {a0.x, a0.y, a0.z, a0.w, a1.x, a1.y, a1.z, a1.w};
      const float* wp = &wt[(dr * 3 + dl) * 128];
#pragma unroll
      for (int ic = 0; ic < 8; ic++) {
#pragma unroll
        for (int oc = 0; oc < 16; oc++)
          acc[oc] = fmaf(xv[ic], wp[ic * 16 + oc], acc[oc]);
      }
    }
  }
#pragma unroll
  for (int oc = 0; oc < 16; oc++) pool_s[t * 17 + oc] = fmaxf(acc[oc], 0.0f);
  __syncthreads();
  if (t < 64) {
    int oc = t >> 2, lb = t & 3;
    float s = 0.0f;
    for (int lr2 = 0; lr2 < 32; lr2++) {
      int t2 = lr2 * 8 + lb * 2;
      s += pool_s[t2 * 17 + oc] + pool_s[(t2 + 1) * 17 + oc];
    }
    partials[(size_t)(oc * 4 + lb) * 9216 + blockIdx.x] = s;
  }
}

__global__ __launch_bounds__(256) void k_pool_final(const float* __restrict__ partials,
                                                    float* __restrict__ flat) {
  int f = blockIdx.x;
  int oc = f >> 4, rb = (f >> 2) & 3, lb = f & 3;
  const float* src = partials + (size_t)(oc * 4 + lb) * 9216 + rb * 2304;
  double s = 0.0;
  for (int i = threadIdx.x; i < 2304; i += 256) s += (double)src[i];
  __shared__ double sd[256];
  sd[threadIdx.x] = s;
  __syncthreads();
  for (int off = 128; off > 0; off >>= 1) {
    if (threadIdx.x < off) sd[threadIdx.x] += sd[threadIdx.x + off];
    __syncthreads();
  }
  if (threadIdx.x == 0) flat[f] = (float)(sd[0] * (1.0 / 147456.0));
}

// one wave per 32 rows of proj_w; also emits sort2 keys+vals
__global__ __launch_bounds__(256) void k_matvec(const float* __restrict__ pw,
                                                const float* __restrict__ pb,
                                                const float* __restrict__ flat,
                                                float* __restrict__ out,
                                                u32* __restrict__ k2, u32* __restrict__ v2) {
  int t = threadIdx.x;
  int lane = t & 63;
  int g = (blockIdx.x * 256 + t) >> 6;
  float4 f4 = ((const float4*)flat)[lane];
  int row0 = g * 32;
  for (int it = 0; it < 32; it += 2) {
    int row = row0 + it;
    float4 wa = ((const float4*)(pw + (size_t)row * 256))[lane];
    float4 wb = ((const float4*)(pw + (size_t)(row + 1) * 256))[lane];
    float sa = wa.x * f4.x + wa.y * f4.y + wa.z * f4.z + wa.w * f4.w;
    float sb = wb.x * f4.x + wb.y * f4.y + wb.z * f4.z + wb.w * f4.w;
#pragma unroll
    for (int off = 32; off > 0; off >>= 1) {
      sa += __shfl_xor(sa, off, 64);
      sb += __shfl_xor(sb, off, 64);
    }
    if (lane == 0) {
      float ra = sa + pb[row], rb2 = sb + pb[row + 1];
      out[row] = ra;
      out[row + 1] = rb2;
      u32 ua = __float_as_uint(ra), ub = __float_as_uint(rb2);
      ua = (ua & 0x80000000u) ? ~ua : (ua | 0x80000000u);
      ub = (ub & 0x80000000u) ? ~ub : (ub | 0x80000000u);
      k2[row] = ua; k2[row + 1] = ub;
      v2[row] = (u32)row; v2[row + 1] = (u32)(row + 1);
    }
  }
}

__device__ inline double staged_pair(float x) {
  float h = fabsf(x);
  double mult = (h <= 2.f) ? 1.0 : (h <= 4.f) ? 1.5 : (h <= 8.f) ? 2.0 : (h <= 16.f) ? 3.0 : 5.0;
  double hh = (double)h;
  if (x > 0.f) return hh * mult;
  if (x < 0.f) return hh * hh * mult;
  return 0.0;
}

// grid barrier: monotonic counter, release/acquire fences (rocPRIM-style).
// All 32 blocks co-resident (32 << 256 CUs), uniform call count.
__device__ __forceinline__ void gb(u32* bar, u32 target, int t) {
  __syncthreads();
  if (t == 0) {
    __threadfence();                 // release
    atomicAdd(bar, 1u);
    while (atomicAdd(bar, 0u) < target) __builtin_amdgcn_s_sleep(1);
    __threadfence();                 // acquire
  }
  __syncthreads();
}

// FUSED sort2 (3 radix passes) + ops emission + penalty + finalize.
// 32 blocks x 512 threads, persistent, device-atomic grid barrier.
__global__ __launch_bounds__(512) void k_sort2(u32* __restrict__ kA, u32* __restrict__ vA,
                                               u32* __restrict__ kB, u32* __restrict__ vB,
                                               u32* __restrict__ gcounts,
                                               const u32* __restrict__ addr,
                                               float4* __restrict__ ops,
                                               double* __restrict__ pgp,
                                               u32* __restrict__ bar,
                                               float* __restrict__ out) {
  __shared__ __attribute__((aligned(16))) char smem[76 * 1024];
  u32* sk = (u32*)smem;                               // 8192
  u32* sv = sk + 8192;                                // 8192
  u32 (*whist)[256] = (u32(*)[256])(sv + 8192);       // 8*256
  u32* sbase  = (u32*)(smem + 72 * 1024);             // 256
  u32* lstart = sbase + 256;                          // 256
  u32* gdelta = lstart + 256;                         // 256
  u32* red    = gdelta + 256;                         // 256
  int t = threadIdx.x, b = blockIdx.x;
  int w = t >> 6, lane = t & 63;
  u64 lowmask = (1ull << lane) - 1ull;
  int base = b * 8192;
  u32 barn = 0;

  for (int pass = 0; pass < 3; pass++) {
    int shift = 8 + pass * 8;
    const u32* kin = (pass == 1) ? kB : kA;
    const u32* vin = (pass == 1) ? vB : vA;
    u32* kout = (pass == 0) ? kB : kA;
    u32* vout = (pass == 0) ? vB : vA;

    // ---- hist (per-block tile) ----
    u32* h = whist[0];
    if (t < 256) h[t] = 0u;
    __syncthreads();
#pragma unroll
    for (int k = 0; k < 16; k++) {
      u32 d = (kin[base + t + k * 512] >> shift) & 255u;
      atomicAdd(&h[d], 1u);
    }
    __syncthreads();
    if (t < 256) gcounts[t * 32 + b] = h[t];
    barn += 32;
    gb(bar, barn, t);

    // ---- scan (per-block redundant over 256x32 counts) ----
    u32 rs = 0, part = 0;
    if (t < 256) {
      for (int bb = 0; bb < 32; bb++) {
        u32 c = gcounts[t * 32 + bb];
        rs += c;
        if (bb < b) part += c;
      }
      red[t] = rs;
    }
    __syncthreads();
    for (int off = 1; off < 256; off <<= 1) {
      u32 y = (t < 256 && t >= off) ? red[t - off] : 0u;
      __syncthreads();
      if (t < 256) red[t] += y;
      __syncthreads();
    }
    if (t < 256) sbase[t] = red[t] - rs + part;
    __syncthreads();

    // ---- rank + LDS reorder ----
    if (t < 256) {
#pragma unroll
      for (int ww = 0; ww < 8; ww++) whist[ww][t] = 0u;
    }
    __syncthreads();
    u32 kk[16], vv[16], dig[16], rnk[16];
#pragma unroll
    for (int j = 0; j < 16; j++) {
      int idx = base + w * 1024 + j * 64 + lane;
      kk[j] = kin[idx];
      vv[j] = vin[idx];
    }
#pragma unroll
    for (int j = 0; j < 16; j++) {
      u32 d = (kk[j] >> shift) & 255u;
      u64 m = ~0ull;
#pragma unroll
      for (int bit = 0; bit < 8; bit++) {
        u64 bal = __ballot((d >> bit) & 1u);
        m &= ((d >> bit) & 1u) ? bal : ~bal;
      }
      u32 rr = (u32)__popcll(m & lowmask);
      u32 cnt = (u32)__popcll(m);
      u32 prev = whist[w][d];
      if (rr == 0) whist[w][d] = prev + cnt;
      dig[j] = d;
      rnk[j] = prev + rr;
    }
    __syncthreads();
    u32 tot = 0;
    if (t < 256) {
      u32 sacc = 0;
#pragma unroll
      for (int ww = 0; ww < 8; ww++) { u32 v = whist[ww][t]; whist[ww][t] = sacc; sacc += v; }
      tot = sacc;
      red[t] = tot;
    }
    __syncthreads();
    for (int off = 1; off < 256; off <<= 1) {
      u32 y = (t < 256 && t >= off) ? red[t - off] : 0u;
      __syncthreads();
      if (t < 256) red[t] += y;
      __syncthreads();
    }
    if (t < 256) {
      u32 lst = red[t] - tot;
      lstart[t] = lst;
      gdelta[t] = sbase[t] - lst;
    }
    __syncthreads();
#pragma unroll
    for (int j = 0; j < 16; j++) {
      u32 d = dig[j];
      u32 lpos = lstart[d] + whist[w][d] + rnk[j];
      sk[lpos] = kk[j];
      sv[lpos] = vv[j];
    }
    __syncthreads();

    // ---- write ----
    if (pass < 2) {
#pragma unroll
      for (int r = 0; r < 16; r++) {
        int idx = t + r * 512;
        u32 key = sk[idx];
        u32 d = (key >> shift) & 255u;
        u32 gpos = gdelta[d] + (u32)idx;
        kout[gpos] = key;
        vout[gpos] = sv[idx];
      }
    } else {
#pragma unroll
      for (int r = 0; r < 16; r++) {
        int idx = t + r * 512;
        u32 key = sk[idx];
        u32 d = (key >> shift) & 255u;
        u32 gpos = gdelta[d] + (u32)idx;
        u32 rv = sv[idx];
        int i = (int)(rv >> 9), jj = (int)(rv & 511);
        float A0 = (float)addr[(i << 10) + jj];
        float A1 = (float)addr[OFF1 + (i << 10) + jj];
        float A2 = (float)addr[OFF2 + (int)rv];
        ops[gpos] = make_float4(A0, A1, A2, 0.0f);
      }
    }
    barn += 32;
    gb(bar, barn, t);
  }

  // ---- penalty (ops fully written) ----
  double i0 = 0.0, i1 = 0.0;
#pragma unroll
  for (int r = 0; r < 16; r++) {
    int k = base + r * 512 + t;
    float4 a = ops[k];
    i1 += staged_pair(a.y - a.x) + staged_pair(a.z - a.y);
    if (k < N_OPS - 1) {
      float4 nb = ops[k + 1];
      i0 += staged_pair(nb.x - a.z);
    }
  }
  double* s0 = (double*)smem;        // 512 doubles
  double* s1 = s0 + 512;             // 512 doubles
  s0[t] = i0;
  s1[t] = i1;
  __syncthreads();
  for (int off = 256; off > 0; off >>= 1) {
    if (t < off) { s0[t] += s0[t + off]; s1[t] += s1[t + off]; }
    __syncthreads();
  }
  if (t == 0) { pgp[b] = s0[0]; pgp[32 + b] = s1[0]; }
  barn += 32;
  gb(bar, barn, t);
  if (b == 0 && t == 0) {
    double a0 = 0.0, a1 = 0.0;
    for (int i2 = 0; i2 < 32; i2++) { a0 += pgp[i2]; a1 += pgp[32 + i2]; }
    out[N_OPS] = (float)a0;
    out[N_OPS + 1] = (float)a1;
  }
}

extern "C" void kernel_launch(void* const* d_in, const int* in_sizes, int n_in,
                              void* d_out, int out_size, void* d_ws, size_t ws_size,
                              hipStream_t stream) {
  const float* mem_logits = (const float*)d_in[0];
  const float* cw0 = (const float*)d_in[1];
  const float* cb0 = (const float*)d_in[2];
  const float* cw1 = (const float*)d_in[3];
  const float* cb1 = (const float*)d_in[4];
  const float* cw2 = (const float*)d_in[5];
  const float* cb2 = (const float*)d_in[6];
  const float* mw  = (const float*)d_in[7];
  const float* mbb = (const float*)d_in[8];
  const float* pw  = (const float*)d_in[9];
  const float* pb  = (const float*)d_in[10];
  float* out = (float*)d_out;
  char* ws = (char*)d_ws;

  u32* addr      = (u32*)(ws);
  u16* featsM    = (u16*)(ws + OFF_F8);
  u32* kA        = (u32*)(ws + OFF_F8);
  u32* kB        = (u32*)(ws + OFF_F8 + 9437184ull);
  u32* v0        = (u32*)(ws + OFF_F8 + 18874368ull);
  u32* v1        = (u32*)(ws + OFF_F8 + 28311552ull);
  u32* counts0   = (u32*)(ws + OFF_C0);
  u32* pos       = (u32*)(ws + OFF_POS);
  float* partials= (float*)(ws + OFF_PART);
  float* flat    = (float*)(ws + OFF_FLAT);
  float* wt      = (float*)(ws + OFF_WT);
  double* pgp    = (double*)(ws + OFF_PGP);
  u32* bar       = (u32*)(ws + OFF_BAR);
  float4* ops    = (float4*)(ws + OFF_OPS);
  u32* k2A       = (u32*)(ws + OFF_S2);
  u32* k2B       = (u32*)(ws + OFF_S2 + 1048576ull);
  u32* v2A       = (u32*)(ws + OFF_S2 + 2097152ull);
  u32* v2B       = (u32*)(ws + OFF_S2 + 3145728ull);

  // ---- sort1: keys + pass-0 hist fused in k_front; passes 1,2 use k_hist (no atomics) ----
  k_front<<<289, 256, 0, stream>>>(mem_logits, kA, counts0, mw, wt, bar);
  k_scan_par<<<256, 256, 0, stream>>>(counts0, pos, 288);
  k_scatter<<<288, 512, 0, stream>>>(kA, nullptr, kB, v0, pos, 8, 288, 1, 0);
  k_hist<<<288, 512, 0, stream>>>(kB, counts0, 16, 288);
  k_scan_par<<<256, 256, 0, stream>>>(counts0, pos, 288);
  k_scatter<<<288, 512, 0, stream>>>(kB, v0, kA, v1, pos, 16, 288, 0, 0);
  k_hist<<<288, 512, 0, stream>>>(kA, counts0, 24, 288);
  k_scan_par<<<256, 256, 0, stream>>>(counts0, pos, 288);
  k_scatter<<<288, 512, 0, stream>>>(kA, v1, nullptr, addr, pos, 24, 288, 0, 1);

  // ---- streaming convs (scatter to memory order), coalesced memconv + pool ----
  k_conv<<<9216, 256, 0, stream>>>(addr, cw0, cb0, cw1, cb1, cw2, cb2, featsM);
  k_memconv<<<9216, 256, 0, stream>>>(featsM, wt, mbb, partials);
  k_pool_final<<<256, 256, 0, stream>>>(partials, flat);

  // ---- projection matvec -> op_logits + sort2 keys ----
  k_matvec<<<2048, 256, 0, stream>>>(pw, pb, flat, out, k2A, v2A);

  // ---- fused sort2 + ops + penalty + finalize (persistent, grid barrier) ----
  k_sort2<<<32, 512, 0, stream>>>(k2A, v2A, k2B, v2B, counts0, addr, ops, pgp, bar, out);
}